// Round 1
// baseline (241.449 us; speedup 1.0000x reference)
//
#include <hip/hip_runtime.h>

// relu(sum(relu(x))) over N=2^25 fp32.
// Stage 1: zero ws accumulator+counter (ws is poisoned 0xAA before every call).
// Stage 2: grid-stride float4 reduction, per-block atomicAdd, last block writes
//          relu(total) to d_out (threadfence + counter pattern, device-scope atomics).

__global__ void kan_init(float* ws_f, unsigned* ws_u) {
    ws_f[0] = 0.0f;
    ws_u[0] = 0u;
}

__global__ __launch_bounds__(256) void kan_reduce(const float* __restrict__ x,
                                                  float* __restrict__ ws_f,
                                                  unsigned* __restrict__ ws_u,
                                                  float* __restrict__ out,
                                                  int n4, unsigned nblocks) {
    const float4* x4 = (const float4*)x;
    int idx = blockIdx.x * blockDim.x + threadIdx.x;
    int stride = blockDim.x * gridDim.x;

    float s = 0.0f;
    for (int i = idx; i < n4; i += stride) {
        float4 v = x4[i];
        s += fmaxf(v.x, 0.0f) + fmaxf(v.y, 0.0f) + fmaxf(v.z, 0.0f) + fmaxf(v.w, 0.0f);
    }

    // wave-64 reduction
    #pragma unroll
    for (int off = 32; off > 0; off >>= 1)
        s += __shfl_down(s, off, 64);

    __shared__ float wsum[4];
    int lane = threadIdx.x & 63;
    int wid  = threadIdx.x >> 6;
    if (lane == 0) wsum[wid] = s;
    __syncthreads();

    if (threadIdx.x == 0) {
        float bs = wsum[0] + wsum[1] + wsum[2] + wsum[3];
        atomicAdd(ws_f, bs);              // device-scope by default on CDNA
        __threadfence();
        unsigned old = atomicAdd(ws_u, 1u);
        if (old == nblocks - 1u) {
            // all blocks' adds are globally visible; read via atomic RMW for coherence
            float total = atomicAdd(ws_f, 0.0f);
            out[0] = fmaxf(total, 0.0f);  // outer ReLU (sum of relus is >=0 anyway)
        }
    }
}

extern "C" void kernel_launch(void* const* d_in, const int* in_sizes, int n_in,
                              void* d_out, int out_size, void* d_ws, size_t ws_size,
                              hipStream_t stream) {
    const float* x = (const float*)d_in[0];
    float* out = (float*)d_out;
    float* ws_f = (float*)d_ws;
    unsigned* ws_u = (unsigned*)d_ws + 1;

    int n = in_sizes[0];          // 33554432
    int n4 = n >> 2;              // 8388608 float4s, exact

    const int block = 256;
    const unsigned nblocks = 2048;  // 8 blocks/CU, grid-stride covers n4

    kan_init<<<1, 1, 0, stream>>>(ws_f, ws_u);
    kan_reduce<<<nblocks, block, 0, stream>>>(x, ws_f, ws_u, out, n4, nblocks);
}

// Round 2
// 189.510 us; speedup vs baseline: 1.2741x; 1.2741x over previous
//
#include <hip/hip_runtime.h>

// relu(sum(relu(x))) over N=2^25 fp32.
// Kernel 1: 2048 blocks x 256 threads, 16 fully-unrolled float4 loads/thread
//           (16 KB in flight per wave), per-block partial -> ws[block] (no atomics).
// Kernel 2: 1 block reduces 2048 partials, applies outer ReLU, writes d_out.

#define NBLOCKS 2048
#define TPB     256
#define PER     16   // float4s per thread: 2048*256*16 = 8M float4 = 2^25 floats

__global__ __launch_bounds__(TPB) void kan_partial(const float4* __restrict__ x4,
                                                   float* __restrict__ partials) {
    const int t = blockIdx.x * TPB + threadIdx.x;
    const int stride = NBLOCKS * TPB;  // 524288 float4s

    // 16 independent loads -> deep MLP; compiler batches them before the adds.
    float s = 0.0f;
    #pragma unroll
    for (int i = 0; i < PER; ++i) {
        float4 v = x4[t + i * stride];
        s += fmaxf(v.x, 0.0f) + fmaxf(v.y, 0.0f) + fmaxf(v.z, 0.0f) + fmaxf(v.w, 0.0f);
    }

    // wave-64 reduction
    #pragma unroll
    for (int off = 32; off > 0; off >>= 1)
        s += __shfl_down(s, off, 64);

    __shared__ float wsum[TPB / 64];
    const int lane = threadIdx.x & 63;
    const int wid  = threadIdx.x >> 6;
    if (lane == 0) wsum[wid] = s;
    __syncthreads();

    if (threadIdx.x == 0)
        partials[blockIdx.x] = wsum[0] + wsum[1] + wsum[2] + wsum[3];
}

__global__ __launch_bounds__(TPB) void kan_final(const float* __restrict__ partials,
                                                 float* __restrict__ out) {
    // 2048 partials, 256 threads -> 8 each
    float s = 0.0f;
    #pragma unroll
    for (int i = 0; i < NBLOCKS / TPB; ++i)
        s += partials[threadIdx.x + i * TPB];

    #pragma unroll
    for (int off = 32; off > 0; off >>= 1)
        s += __shfl_down(s, off, 64);

    __shared__ float wsum[TPB / 64];
    const int lane = threadIdx.x & 63;
    const int wid  = threadIdx.x >> 6;
    if (lane == 0) wsum[wid] = s;
    __syncthreads();

    if (threadIdx.x == 0) {
        float total = wsum[0] + wsum[1] + wsum[2] + wsum[3];
        out[0] = fmaxf(total, 0.0f);
    }
}

extern "C" void kernel_launch(void* const* d_in, const int* in_sizes, int n_in,
                              void* d_out, int out_size, void* d_ws, size_t ws_size,
                              hipStream_t stream) {
    const float4* x4 = (const float4*)d_in[0];
    float* out = (float*)d_out;
    float* partials = (float*)d_ws;  // 2048 floats, all written by kan_partial

    kan_partial<<<NBLOCKS, TPB, 0, stream>>>(x4, partials);
    kan_final<<<1, TPB, 0, stream>>>(partials, out);
}

// Round 4
// 181.378 us; speedup vs baseline: 1.3312x; 1.0448x over previous
//
#include <hip/hip_runtime.h>

// relu(sum(relu(x))) over N=2^25 fp32.
// Kernel 1: 2048 blocks x 256 threads. Two-phase per thread: batch-issue 16
//           nontemporal float4 loads into a register array (forces all 16 in
//           flight before first use -> ~16 KB MLP per wave), then 4-accumulator
//           relu+sum tree. Per-block partial -> ws[block], plain store.
// Kernel 2: 1 block reduces 2048 partials, applies outer ReLU.
//
// Note: __builtin_nontemporal_load needs a native vector type, not HIP's
// float4 class -> use ext_vector_type(4).

typedef float f32x4 __attribute__((ext_vector_type(4)));

#define NBLOCKS 2048
#define TPB     256
#define PER     16   // 2048*256*16 float4 = 2^25 floats, exact

__global__ __launch_bounds__(TPB) void kan_partial(const f32x4* __restrict__ x4,
                                                   float* __restrict__ partials) {
    const int t = blockIdx.x * TPB + threadIdx.x;
    const int stride = NBLOCKS * TPB;  // 524288 float4s = 8 MB slab per i

    // Phase 1: issue all 16 loads with no intervening consumer.
    f32x4 v[PER];
    #pragma unroll
    for (int i = 0; i < PER; ++i)
        v[i] = __builtin_nontemporal_load(&x4[t + i * stride]);

    // Phase 2: 4 independent accumulator chains.
    float s0 = 0.0f, s1 = 0.0f, s2 = 0.0f, s3 = 0.0f;
    #pragma unroll
    for (int i = 0; i < PER; i += 4) {
        s0 += fmaxf(v[i+0].x, 0.0f) + fmaxf(v[i+0].y, 0.0f) + fmaxf(v[i+0].z, 0.0f) + fmaxf(v[i+0].w, 0.0f);
        s1 += fmaxf(v[i+1].x, 0.0f) + fmaxf(v[i+1].y, 0.0f) + fmaxf(v[i+1].z, 0.0f) + fmaxf(v[i+1].w, 0.0f);
        s2 += fmaxf(v[i+2].x, 0.0f) + fmaxf(v[i+2].y, 0.0f) + fmaxf(v[i+2].z, 0.0f) + fmaxf(v[i+2].w, 0.0f);
        s3 += fmaxf(v[i+3].x, 0.0f) + fmaxf(v[i+3].y, 0.0f) + fmaxf(v[i+3].z, 0.0f) + fmaxf(v[i+3].w, 0.0f);
    }
    float s = (s0 + s1) + (s2 + s3);

    // wave-64 reduction
    #pragma unroll
    for (int off = 32; off > 0; off >>= 1)
        s += __shfl_down(s, off, 64);

    __shared__ float wsum[TPB / 64];
    const int lane = threadIdx.x & 63;
    const int wid  = threadIdx.x >> 6;
    if (lane == 0) wsum[wid] = s;
    __syncthreads();

    if (threadIdx.x == 0)
        partials[blockIdx.x] = wsum[0] + wsum[1] + wsum[2] + wsum[3];
}

__global__ __launch_bounds__(TPB) void kan_final(const float* __restrict__ partials,
                                                 float* __restrict__ out) {
    // 2048 partials, 256 threads -> 8 each; batch loads, then add.
    float p[NBLOCKS / TPB];
    #pragma unroll
    for (int i = 0; i < NBLOCKS / TPB; ++i)
        p[i] = partials[threadIdx.x + i * TPB];

    float s = 0.0f;
    #pragma unroll
    for (int i = 0; i < NBLOCKS / TPB; ++i)
        s += p[i];

    #pragma unroll
    for (int off = 32; off > 0; off >>= 1)
        s += __shfl_down(s, off, 64);

    __shared__ float wsum[TPB / 64];
    const int lane = threadIdx.x & 63;
    const int wid  = threadIdx.x >> 6;
    if (lane == 0) wsum[wid] = s;
    __syncthreads();

    if (threadIdx.x == 0) {
        float total = wsum[0] + wsum[1] + wsum[2] + wsum[3];
        out[0] = fmaxf(total, 0.0f);
    }
}

extern "C" void kernel_launch(void* const* d_in, const int* in_sizes, int n_in,
                              void* d_out, int out_size, void* d_ws, size_t ws_size,
                              hipStream_t stream) {
    const f32x4* x4 = (const f32x4*)d_in[0];
    float* out = (float*)d_out;
    float* partials = (float*)d_ws;  // 2048 floats, all written by kan_partial

    kan_partial<<<NBLOCKS, TPB, 0, stream>>>(x4, partials);
    kan_final<<<1, TPB, 0, stream>>>(partials, out);
}